// Round 1
// baseline (598.744 us; speedup 1.0000x reference)
//
#include <hip/hip_runtime.h>
#include <stdint.h>

#define TOKENS 8192
#define OUT_F  4096
#define IN_F   4096
#define RNK    8
#define KPRUNE 8388608u

typedef unsigned short u16;
typedef float  f32x4  __attribute__((ext_vector_type(4)));
typedef short  bf16x8 __attribute__((ext_vector_type(8)));
typedef unsigned short u16x8 __attribute__((ext_vector_type(8)));

// ---- workspace layout (bytes) ----
#define XB_OFF    0ull                 // xB  : 8192*4096 bf16 = 64 MiB
#define WB_OFF    67108864ull          // wB  : 4096*4096 bf16 = 32 MiB
#define KEYS_OFF  100663296ull         // keys: 4096*4096 u32  = 64 MiB
#define CTL_OFF   167772160ull
//   ctl region (zeroed each launch): h1[4096] h2[4096] h3[256] sel[8]
#define H1_OFF    0
#define H2_OFF    16384
#define H3_OFF    32768
#define SEL_OFF   33792
#define CTL_ZERO_U32 8456              // (16384+16384+1024+32)/4
#define TIES_OFF  33824                // ties[4096] u32 (fully rewritten each launch)

__device__ __forceinline__ u16 f2bf(float f) {
    uint32_t u = __float_as_uint(f);
    u += 0x7fffu + ((u >> 16) & 1u);   // RNE
    return (u16)(u >> 16);
}

// monotone key: float total-order -> u32 ascending
__device__ __forceinline__ uint32_t fkey(float s) {
    uint32_t u = __float_as_uint(s);
    return (u & 0x80000000u) ? ~u : (u | 0x80000000u);
}

// ---------------- zero ctl ----------------
__global__ void zero_kernel(uint32_t* __restrict__ p, int n)
{
    int i = blockIdx.x * 256 + threadIdx.x;
    if (i < n) p[i] = 0u;
}

// ---------------- x -> bf16 ----------------
__global__ void convx_kernel(const float* __restrict__ x, u16* __restrict__ xB)
{
    const size_t idx = (size_t)blockIdx.x * 256 + threadIdx.x;   // 4,194,304 total
    const float4* xv = (const float4*)x;
    float4 a = xv[idx*2];
    float4 b = xv[idx*2 + 1];
    u16x8 o;
    o[0]=f2bf(a.x); o[1]=f2bf(a.y); o[2]=f2bf(a.z); o[3]=f2bf(a.w);
    o[4]=f2bf(b.x); o[5]=f2bf(b.y); o[6]=f2bf(b.z); o[7]=f2bf(b.w);
    *((u16x8*)xB + idx) = o;
}

// ---------------- prep: w, keys, bf16 w, 12-bit histogram ----------------
// one block per output row o
__global__ void prep_kernel(const float* __restrict__ W, const float* __restrict__ U,
                            const float* __restrict__ V, const float* __restrict__ A,
                            const float* __restrict__ B, const float* __restrict__ R,
                            const float* __restrict__ C, u16* __restrict__ wB,
                            uint32_t* __restrict__ keys, uint32_t* __restrict__ hist1)
{
    __shared__ uint32_t lh[4096];
    const int o = blockIdx.x, t = threadIdx.x;
    for (int b = t; b < 4096; b += 256) lh[b] = 0u;
    float uu[RNK], aa[RNK];
#pragma unroll
    for (int r = 0; r < RNK; ++r) { uu[r] = U[o*RNK + r]; aa[r] = A[o*RNK + r]; }
    const float ro = R[o];
    __syncthreads();
    for (int j = 0; j < IN_F/256; ++j) {
        const int i = j*256 + t;
        float wv = W[(size_t)o*IN_F + i];
#pragma unroll
        for (int r = 0; r < RNK; ++r) wv = fmaf(uu[r], V[r*IN_F + i], wv);
        float s = fabsf(wv);
#pragma unroll
        for (int r = 0; r < RNK; ++r) s = fmaf(aa[r], B[r*IN_F + i], s);
        s += ro + C[i];
        const uint32_t key = fkey(s);
        keys[(size_t)o*IN_F + i] = key;
        wB[(size_t)o*IN_F + i]   = f2bf(wv);
        atomicAdd(&lh[key >> 20], 1u);
    }
    __syncthreads();
    for (int b = t; b < 4096; b += 256) { uint32_t c = lh[b]; if (c) atomicAdd(&hist1[b], c); }
}

// ---------------- k-th select over a histogram (parallel 2-level scan) ----------------
// mode 0: hist1 (4096 bins, key>>20),      k=KPRUNE        -> sel[0]=b1, sel[1]=count_below
// mode 1: hist2 (4096 bins, (key>>8)&FFF), k=KPRUNE-sel[1] -> sel[2]=b2, sel[3]=total_below
// mode 2: hist3 (256 bins,  key&FF),       k=KPRUNE-sel[3] -> sel[4]=thr_key, sel[5]=p (#ties to prune)
__global__ void select_kernel(const uint32_t* __restrict__ hist, uint32_t* sel, int nbins, int mode)
{
    __shared__ uint32_t lh[4096];
    __shared__ uint32_t part[256];
    __shared__ uint32_t sseg[2];
    const int t = threadIdx.x;
    const uint32_t b1v = sel[0], c1v = sel[1], b2v = sel[2], c3v = sel[3]; // garbage in early modes: unused
    uint32_t k;
    if (mode == 0)      k = KPRUNE;
    else if (mode == 1) k = KPRUNE - c1v;
    else                k = KPRUNE - c3v;
    for (int b = t; b < nbins; b += 256) lh[b] = hist[b];
    __syncthreads();
    const int per = nbins >> 8;              // 16 or 1
    uint32_t s = 0;
    for (int j = 0; j < per; ++j) s += lh[t*per + j];
    part[t] = s;
    __syncthreads();
    uint32_t pre = 0;
    for (int tt = 0; tt < t; ++tt) pre += part[tt];  // independent LDS reads, pipelined
    if (pre < k && pre + part[t] >= k) { sseg[0] = (uint32_t)t; sseg[1] = pre; }
    __syncthreads();
    const int seg = (int)sseg[0];
    const uint32_t accb = sseg[1];
    if (t < per) {
        uint32_t pre2 = 0;
        for (int j = 0; j < t; ++j) pre2 += lh[seg*per + j];
        const uint32_t c = lh[seg*per + t];
        const uint32_t below = accb + pre2;
        if (below < k && below + c >= k) {
            const uint32_t bin = (uint32_t)(seg*per + t);
            if (mode == 0)      { sel[0] = bin; sel[1] = below; }
            else if (mode == 1) { sel[2] = bin; sel[3] = c1v + below; }
            else {
                sel[4] = (b1v << 20) | (b2v << 8) | bin;  // exact threshold key
                sel[5] = k - below;                        // ties to prune (>=1)
            }
        }
    }
}

// ---------------- hist level 2 ----------------
__global__ void hist2_kernel(const uint32_t* __restrict__ keys, const uint32_t* __restrict__ sel,
                             uint32_t* __restrict__ hist2)
{
    __shared__ uint32_t lh[4096];
    const int o = blockIdx.x, t = threadIdx.x;
    const uint32_t b1 = sel[0];
    for (int b = t; b < 4096; b += 256) lh[b] = 0u;
    __syncthreads();
    const uint32_t* kp = keys + (size_t)o*IN_F + t*16;
#pragma unroll
    for (int q = 0; q < 4; ++q) {
        uint4 kv = *(const uint4*)(kp + q*4);
        if ((kv.x >> 20) == b1) atomicAdd(&lh[(kv.x >> 8) & 0xFFFu], 1u);
        if ((kv.y >> 20) == b1) atomicAdd(&lh[(kv.y >> 8) & 0xFFFu], 1u);
        if ((kv.z >> 20) == b1) atomicAdd(&lh[(kv.z >> 8) & 0xFFFu], 1u);
        if ((kv.w >> 20) == b1) atomicAdd(&lh[(kv.w >> 8) & 0xFFFu], 1u);
    }
    __syncthreads();
    for (int b = t; b < 4096; b += 256) { uint32_t c = lh[b]; if (c) atomicAdd(&hist2[b], c); }
}

// ---------------- hist level 3 ----------------
__global__ void hist3_kernel(const uint32_t* __restrict__ keys, const uint32_t* __restrict__ sel,
                             uint32_t* __restrict__ hist3)
{
    __shared__ uint32_t lh[256];
    const int o = blockIdx.x, t = threadIdx.x;
    const uint32_t pfx = (sel[0] << 12) | sel[2];   // key>>8 prefix
    lh[t] = 0u;
    __syncthreads();
    const uint32_t* kp = keys + (size_t)o*IN_F + t*16;
#pragma unroll
    for (int q = 0; q < 4; ++q) {
        uint4 kv = *(const uint4*)(kp + q*4);
        if ((kv.x >> 8) == pfx) atomicAdd(&lh[kv.x & 0xFFu], 1u);
        if ((kv.y >> 8) == pfx) atomicAdd(&lh[kv.y & 0xFFu], 1u);
        if ((kv.z >> 8) == pfx) atomicAdd(&lh[kv.z & 0xFFu], 1u);
        if ((kv.w >> 8) == pfx) atomicAdd(&lh[kv.w & 0xFFu], 1u);
    }
    __syncthreads();
    uint32_t c = lh[t];
    if (c) atomicAdd(&hist3[t], c);
}

// ---------------- per-row tie counts ----------------
__global__ void tiecount_kernel(const uint32_t* __restrict__ keys, const uint32_t* __restrict__ sel,
                                uint32_t* __restrict__ ties)
{
    __shared__ uint32_t part[256];
    const int o = blockIdx.x, t = threadIdx.x;
    const uint32_t thr = sel[4];
    const uint32_t* kp = keys + (size_t)o*IN_F + t*16;
    uint32_t cnt = 0;
#pragma unroll
    for (int q = 0; q < 4; ++q) {
        uint4 kv = *(const uint4*)(kp + q*4);
        cnt += (kv.x == thr) + (kv.y == thr) + (kv.z == thr) + (kv.w == thr);
    }
    part[t] = cnt;
    __syncthreads();
    if (t == 0) {
        uint32_t s = 0;
        for (int tt = 0; tt < 256; ++tt) s += part[tt];
        ties[o] = s;
    }
}

// ---------------- exclusive scan of per-row tie counts (flat order) ----------------
__global__ void scanties_kernel(uint32_t* __restrict__ ties)
{
    __shared__ uint32_t part[256];
    const int t = threadIdx.x;
    uint32_t v[16]; uint32_t s = 0;
#pragma unroll
    for (int e = 0; e < 16; ++e) { v[e] = ties[t*16 + e]; s += v[e]; }
    part[t] = s;
    __syncthreads();
    uint32_t pre = 0;
    for (int tt = 0; tt < t; ++tt) pre += part[tt];
#pragma unroll
    for (int e = 0; e < 16; ++e) { uint32_t c = v[e]; ties[t*16 + e] = pre; pre += c; }
}

// ---------------- apply mask to bf16 weights (exact stable tie-break) ----------------
// thread t owns contiguous flat chunk [t*16, t*16+16) of its row -> flat-order ranks
__global__ void maskpack_kernel(const uint32_t* __restrict__ keys, const uint32_t* __restrict__ sel,
                                const uint32_t* __restrict__ ties, u16* __restrict__ wB)
{
    __shared__ uint32_t part[256];
    const int o = blockIdx.x, t = threadIdx.x;
    const uint32_t thr = sel[4], p = sel[5];
    const size_t base = (size_t)o*IN_F + t*16;
    uint32_t kv[16];
#pragma unroll
    for (int q = 0; q < 4; ++q) *(uint4*)(kv + q*4) = *(const uint4*)(keys + base + q*4);
    uint32_t cnt = 0;
#pragma unroll
    for (int e = 0; e < 16; ++e) cnt += (kv[e] == thr) ? 1u : 0u;
    part[t] = cnt;
    __syncthreads();
    uint32_t r = ties[o];
    for (int tt = 0; tt < t; ++tt) r += part[tt];
    uint4 wraw[2];
    wraw[0] = *(const uint4*)((const u16*)wB + base);
    wraw[1] = *(const uint4*)((const u16*)wB + base + 8);
    u16* wv = (u16*)wraw;
#pragma unroll
    for (int e = 0; e < 16; ++e) {
        bool prune;
        if (kv[e] < thr)      prune = true;
        else if (kv[e] > thr) prune = false;
        else { prune = (r < p); r += 1u; }
        if (prune) wv[e] = 0u;
    }
    *(uint4*)(wB + base)     = wraw[0];
    *(uint4*)(wB + base + 8) = wraw[1];
}

// ---------------- bf16 NT GEMM: out = xB @ wB^T + bias ----------------
// 128x128 tile, BK=32, 4 waves (2x2), mfma_f32_16x16x32_bf16, global_load_lds staging
__global__ __launch_bounds__(256) void gemm_kernel(const u16* __restrict__ xB,
                                                   const u16* __restrict__ wB,
                                                   const float* __restrict__ bias,
                                                   float* __restrict__ out)
{
    __shared__ u16 As[128*32];   // 8 KiB
    __shared__ u16 Bs[128*32];   // 8 KiB
    const int t    = threadIdx.x;
    const int lane = t & 63;
    const int wid  = t >> 6;
    const int wm   = wid >> 1, wn = wid & 1;
    const int bid  = blockIdx.x;
    const int bn   = bid & 31;   // N/128 = 32
    const int bm   = bid >> 5;   // M/128 = 64

    const int f0   = t * 16;     // byte offset in 4 KiB half-tile
    const int row0 = f0 >> 6;    // 64B per row (32 bf16)
    const int cb   = f0 & 63;

    const char* gA0 = (const char*)(xB + (size_t)(bm*128 + row0)      * IN_F) + cb;
    const char* gA1 = (const char*)(xB + (size_t)(bm*128 + row0 + 64) * IN_F) + cb;
    const char* gB0 = (const char*)(wB + (size_t)(bn*128 + row0)      * IN_F) + cb;
    const char* gB1 = (const char*)(wB + (size_t)(bn*128 + row0 + 64) * IN_F) + cb;
    char* lA0 = (char*)As + f0;
    char* lA1 = (char*)As + f0 + 4096;
    char* lB0 = (char*)Bs + f0;
    char* lB1 = (char*)Bs + f0 + 4096;

    f32x4 acc[4][4] = {};

    const int frow = lane & 15;
    const int fk   = (lane >> 4) << 3;          // 0,8,16,24
    const u16* Ab = As + (wm*64 + frow)*32 + fk;
    const u16* Bb = Bs + (wn*64 + frow)*32 + fk;

    for (int kt = 0; kt < IN_F/32; ++kt) {
        const int koff = kt * 64;               // bytes along K
        __syncthreads();
        __builtin_amdgcn_global_load_lds((const __attribute__((address_space(1))) void*)(gA0 + koff),
                                         (__attribute__((address_space(3))) void*)lA0, 16, 0, 0);
        __builtin_amdgcn_global_load_lds((const __attribute__((address_space(1))) void*)(gA1 + koff),
                                         (__attribute__((address_space(3))) void*)lA1, 16, 0, 0);
        __builtin_amdgcn_global_load_lds((const __attribute__((address_space(1))) void*)(gB0 + koff),
                                         (__attribute__((address_space(3))) void*)lB0, 16, 0, 0);
        __builtin_amdgcn_global_load_lds((const __attribute__((address_space(1))) void*)(gB1 + koff),
                                         (__attribute__((address_space(3))) void*)lB1, 16, 0, 0);
        __syncthreads();
        bf16x8 a[4], b[4];
#pragma unroll
        for (int mi = 0; mi < 4; ++mi) a[mi] = *(const bf16x8*)(Ab + mi*512);
#pragma unroll
        for (int ni = 0; ni < 4; ++ni) b[ni] = *(const bf16x8*)(Bb + ni*512);
#pragma unroll
        for (int mi = 0; mi < 4; ++mi)
#pragma unroll
            for (int ni = 0; ni < 4; ++ni)
                acc[mi][ni] = __builtin_amdgcn_mfma_f32_16x16x32_bf16(a[mi], b[ni], acc[mi][ni], 0, 0, 0);
    }

    // epilogue: C/D layout col=lane&15, row=(lane>>4)*4+q  [m89-verified]
    const int orow = bm*128 + wm*64 + ((lane >> 4) << 2);
    const int ocol = bn*128 + wn*64 + (lane & 15);
#pragma unroll
    for (int ni = 0; ni < 4; ++ni) {
        const int col = ocol + ni*16;
        const float bv = bias[col];
#pragma unroll
        for (int mi = 0; mi < 4; ++mi) {
            const int r0 = orow + mi*16;
            f32x4 v = acc[mi][ni];
#pragma unroll
            for (int q = 0; q < 4; ++q)
                out[(size_t)(r0 + q)*OUT_F + col] = v[q] + bv;
        }
    }
}

extern "C" void kernel_launch(void* const* d_in, const int* in_sizes, int n_in,
                              void* d_out, int out_size, void* d_ws, size_t ws_size,
                              hipStream_t stream)
{
    const float* x    = (const float*)d_in[0];
    const float* W    = (const float*)d_in[1];
    const float* bias = (const float*)d_in[2];
    const float* U    = (const float*)d_in[3];
    const float* V    = (const float*)d_in[4];
    const float* A    = (const float*)d_in[5];
    const float* B    = (const float*)d_in[6];
    const float* R    = (const float*)d_in[7];
    const float* C    = (const float*)d_in[8];
    float* out = (float*)d_out;

    char* ws = (char*)d_ws;
    u16*      xB   = (u16*)(ws + XB_OFF);
    u16*      wB   = (u16*)(ws + WB_OFF);
    uint32_t* keys = (uint32_t*)(ws + KEYS_OFF);
    uint32_t* ctl  = (uint32_t*)(ws + CTL_OFF);
    uint32_t* h1   = (uint32_t*)((char*)ctl + H1_OFF);
    uint32_t* h2   = (uint32_t*)((char*)ctl + H2_OFF);
    uint32_t* h3   = (uint32_t*)((char*)ctl + H3_OFF);
    uint32_t* sel  = (uint32_t*)((char*)ctl + SEL_OFF);
    uint32_t* ties = (uint32_t*)((char*)ctl + TIES_OFF);

    zero_kernel<<<(CTL_ZERO_U32 + 255)/256, 256, 0, stream>>>(ctl, CTL_ZERO_U32);
    convx_kernel<<<TOKENS*IN_F/8/256, 256, 0, stream>>>(x, xB);
    prep_kernel<<<OUT_F, 256, 0, stream>>>(W, U, V, A, B, R, C, wB, keys, h1);
    select_kernel<<<1, 256, 0, stream>>>(h1, sel, 4096, 0);
    hist2_kernel<<<OUT_F, 256, 0, stream>>>(keys, sel, h2);
    select_kernel<<<1, 256, 0, stream>>>(h2, sel, 4096, 1);
    hist3_kernel<<<OUT_F, 256, 0, stream>>>(keys, sel, h3);
    select_kernel<<<1, 256, 0, stream>>>(h3, sel, 256, 2);
    tiecount_kernel<<<OUT_F, 256, 0, stream>>>(keys, sel, ties);
    scanties_kernel<<<1, 256, 0, stream>>>(ties);
    maskpack_kernel<<<OUT_F, 256, 0, stream>>>(keys, sel, ties, wB);
    gemm_kernel<<<(TOKENS/128)*(OUT_F/128), 256, 0, stream>>>(xB, wB, bias, out);
}

// Round 2
// 514.548 us; speedup vs baseline: 1.1636x; 1.1636x over previous
//
#include <hip/hip_runtime.h>
#include <stdint.h>

#define TOKENS 8192
#define OUT_F  4096
#define IN_F   4096
#define RNK    8
#define KPRUNE 8388608u

typedef unsigned short u16;
typedef float  f32x4  __attribute__((ext_vector_type(4)));
typedef short  bf16x8 __attribute__((ext_vector_type(8)));
typedef unsigned short u16x8 __attribute__((ext_vector_type(8)));

// ---- workspace layout (bytes) ----
#define XB_OFF    0ull                 // xB  : 8192*4096 bf16 = 64 MiB
#define WB_OFF    67108864ull          // wB  : 4096*4096 bf16 = 32 MiB
#define KEYS_OFF  100663296ull         // keys: 4096*4096 u32  = 64 MiB
#define CTL_OFF   167772160ull
#define H1_OFF    0
#define H2_OFF    16384
#define H3_OFF    32768
#define SEL_OFF   33792
#define CTL_ZERO_U32 8456
#define TIES_OFF  33824

__device__ __forceinline__ u16 f2bf(float f) {
    uint32_t u = __float_as_uint(f);
    u += 0x7fffu + ((u >> 16) & 1u);   // RNE
    return (u16)(u >> 16);
}

__device__ __forceinline__ uint32_t fkey(float s) {
    uint32_t u = __float_as_uint(s);
    return (u & 0x80000000u) ? ~u : (u | 0x80000000u);
}

// ---------------- zero ctl ----------------
__global__ void zero_kernel(uint32_t* __restrict__ p, int n)
{
    int i = blockIdx.x * 256 + threadIdx.x;
    if (i < n) p[i] = 0u;
}

// ---------------- x -> bf16 ----------------
__global__ void convx_kernel(const float* __restrict__ x, u16* __restrict__ xB)
{
    const size_t idx = (size_t)blockIdx.x * 256 + threadIdx.x;
    const float4* xv = (const float4*)x;
    float4 a = xv[idx*2];
    float4 b = xv[idx*2 + 1];
    u16x8 o;
    o[0]=f2bf(a.x); o[1]=f2bf(a.y); o[2]=f2bf(a.z); o[3]=f2bf(a.w);
    o[4]=f2bf(b.x); o[5]=f2bf(b.y); o[6]=f2bf(b.z); o[7]=f2bf(b.w);
    *((u16x8*)xB + idx) = o;
}

// ---------------- prep: w, keys, bf16 w, 12-bit histogram ----------------
__global__ void prep_kernel(const float* __restrict__ W, const float* __restrict__ U,
                            const float* __restrict__ V, const float* __restrict__ A,
                            const float* __restrict__ B, const float* __restrict__ R,
                            const float* __restrict__ C, u16* __restrict__ wB,
                            uint32_t* __restrict__ keys, uint32_t* __restrict__ hist1)
{
    __shared__ uint32_t lh[4096];
    const int o = blockIdx.x, t = threadIdx.x;
    for (int b = t; b < 4096; b += 256) lh[b] = 0u;
    float uu[RNK], aa[RNK];
#pragma unroll
    for (int r = 0; r < RNK; ++r) { uu[r] = U[o*RNK + r]; aa[r] = A[o*RNK + r]; }
    const float ro = R[o];
    __syncthreads();
    for (int j = 0; j < IN_F/256; ++j) {
        const int i = j*256 + t;
        float wv = W[(size_t)o*IN_F + i];
#pragma unroll
        for (int r = 0; r < RNK; ++r) wv = fmaf(uu[r], V[r*IN_F + i], wv);
        float s = fabsf(wv);
#pragma unroll
        for (int r = 0; r < RNK; ++r) s = fmaf(aa[r], B[r*IN_F + i], s);
        s += ro + C[i];
        const uint32_t key = fkey(s);
        keys[(size_t)o*IN_F + i] = key;
        wB[(size_t)o*IN_F + i]   = f2bf(wv);
        atomicAdd(&lh[key >> 20], 1u);
    }
    __syncthreads();
    for (int b = t; b < 4096; b += 256) { uint32_t c = lh[b]; if (c) atomicAdd(&hist1[b], c); }
}

// ---------------- k-th select over a histogram ----------------
__global__ void select_kernel(const uint32_t* __restrict__ hist, uint32_t* sel, int nbins, int mode)
{
    __shared__ uint32_t lh[4096];
    __shared__ uint32_t part[256];
    __shared__ uint32_t sseg[2];
    const int t = threadIdx.x;
    const uint32_t b1v = sel[0], c1v = sel[1], b2v = sel[2], c3v = sel[3];
    uint32_t k;
    if (mode == 0)      k = KPRUNE;
    else if (mode == 1) k = KPRUNE - c1v;
    else                k = KPRUNE - c3v;
    for (int b = t; b < nbins; b += 256) lh[b] = hist[b];
    __syncthreads();
    const int per = nbins >> 8;
    uint32_t s = 0;
    for (int j = 0; j < per; ++j) s += lh[t*per + j];
    part[t] = s;
    __syncthreads();
    uint32_t pre = 0;
    for (int tt = 0; tt < t; ++tt) pre += part[tt];
    if (pre < k && pre + part[t] >= k) { sseg[0] = (uint32_t)t; sseg[1] = pre; }
    __syncthreads();
    const int seg = (int)sseg[0];
    const uint32_t accb = sseg[1];
    if (t < per) {
        uint32_t pre2 = 0;
        for (int j = 0; j < t; ++j) pre2 += lh[seg*per + j];
        const uint32_t c = lh[seg*per + t];
        const uint32_t below = accb + pre2;
        if (below < k && below + c >= k) {
            const uint32_t bin = (uint32_t)(seg*per + t);
            if (mode == 0)      { sel[0] = bin; sel[1] = below; }
            else if (mode == 1) { sel[2] = bin; sel[3] = c1v + below; }
            else {
                sel[4] = (b1v << 20) | (b2v << 8) | bin;
                sel[5] = k - below;
            }
        }
    }
}

// ---------------- hist level 2 ----------------
__global__ void hist2_kernel(const uint32_t* __restrict__ keys, const uint32_t* __restrict__ sel,
                             uint32_t* __restrict__ hist2)
{
    __shared__ uint32_t lh[4096];
    const int o = blockIdx.x, t = threadIdx.x;
    const uint32_t b1 = sel[0];
    for (int b = t; b < 4096; b += 256) lh[b] = 0u;
    __syncthreads();
    const uint32_t* kp = keys + (size_t)o*IN_F + t*16;
#pragma unroll
    for (int q = 0; q < 4; ++q) {
        uint4 kv = *(const uint4*)(kp + q*4);
        if ((kv.x >> 20) == b1) atomicAdd(&lh[(kv.x >> 8) & 0xFFFu], 1u);
        if ((kv.y >> 20) == b1) atomicAdd(&lh[(kv.y >> 8) & 0xFFFu], 1u);
        if ((kv.z >> 20) == b1) atomicAdd(&lh[(kv.z >> 8) & 0xFFFu], 1u);
        if ((kv.w >> 20) == b1) atomicAdd(&lh[(kv.w >> 8) & 0xFFFu], 1u);
    }
    __syncthreads();
    for (int b = t; b < 4096; b += 256) { uint32_t c = lh[b]; if (c) atomicAdd(&hist2[b], c); }
}

// ---------------- hist level 3 ----------------
__global__ void hist3_kernel(const uint32_t* __restrict__ keys, const uint32_t* __restrict__ sel,
                             uint32_t* __restrict__ hist3)
{
    __shared__ uint32_t lh[256];
    const int o = blockIdx.x, t = threadIdx.x;
    const uint32_t pfx = (sel[0] << 12) | sel[2];
    lh[t] = 0u;
    __syncthreads();
    const uint32_t* kp = keys + (size_t)o*IN_F + t*16;
#pragma unroll
    for (int q = 0; q < 4; ++q) {
        uint4 kv = *(const uint4*)(kp + q*4);
        if ((kv.x >> 8) == pfx) atomicAdd(&lh[kv.x & 0xFFu], 1u);
        if ((kv.y >> 8) == pfx) atomicAdd(&lh[kv.y & 0xFFu], 1u);
        if ((kv.z >> 8) == pfx) atomicAdd(&lh[kv.z & 0xFFu], 1u);
        if ((kv.w >> 8) == pfx) atomicAdd(&lh[kv.w & 0xFFu], 1u);
    }
    __syncthreads();
    uint32_t c = lh[t];
    if (c) atomicAdd(&hist3[t], c);
}

// ---------------- per-row tie counts ----------------
__global__ void tiecount_kernel(const uint32_t* __restrict__ keys, const uint32_t* __restrict__ sel,
                                uint32_t* __restrict__ ties)
{
    __shared__ uint32_t part[256];
    const int o = blockIdx.x, t = threadIdx.x;
    const uint32_t thr = sel[4];
    const uint32_t* kp = keys + (size_t)o*IN_F + t*16;
    uint32_t cnt = 0;
#pragma unroll
    for (int q = 0; q < 4; ++q) {
        uint4 kv = *(const uint4*)(kp + q*4);
        cnt += (kv.x == thr) + (kv.y == thr) + (kv.z == thr) + (kv.w == thr);
    }
    part[t] = cnt;
    __syncthreads();
    if (t == 0) {
        uint32_t s = 0;
        for (int tt = 0; tt < 256; ++tt) s += part[tt];
        ties[o] = s;
    }
}

// ---------------- exclusive scan of per-row tie counts ----------------
__global__ void scanties_kernel(uint32_t* __restrict__ ties)
{
    __shared__ uint32_t part[256];
    const int t = threadIdx.x;
    uint32_t v[16]; uint32_t s = 0;
#pragma unroll
    for (int e = 0; e < 16; ++e) { v[e] = ties[t*16 + e]; s += v[e]; }
    part[t] = s;
    __syncthreads();
    uint32_t pre = 0;
    for (int tt = 0; tt < t; ++tt) pre += part[tt];
#pragma unroll
    for (int e = 0; e < 16; ++e) { uint32_t c = v[e]; ties[t*16 + e] = pre; pre += c; }
}

// ---------------- apply mask to bf16 weights (exact stable tie-break) ----------------
__global__ void maskpack_kernel(const uint32_t* __restrict__ keys, const uint32_t* __restrict__ sel,
                                const uint32_t* __restrict__ ties, u16* __restrict__ wB)
{
    __shared__ uint32_t part[256];
    const int o = blockIdx.x, t = threadIdx.x;
    const uint32_t thr = sel[4], p = sel[5];
    const size_t base = (size_t)o*IN_F + t*16;
    uint32_t kv[16];
#pragma unroll
    for (int q = 0; q < 4; ++q) *(uint4*)(kv + q*4) = *(const uint4*)(keys + base + q*4);
    uint32_t cnt = 0;
#pragma unroll
    for (int e = 0; e < 16; ++e) cnt += (kv[e] == thr) ? 1u : 0u;
    part[t] = cnt;
    __syncthreads();
    uint32_t r = ties[o];
    for (int tt = 0; tt < t; ++tt) r += part[tt];
    uint4 wraw[2];
    wraw[0] = *(const uint4*)((const u16*)wB + base);
    wraw[1] = *(const uint4*)((const u16*)wB + base + 8);
    u16* wv = (u16*)wraw;
#pragma unroll
    for (int e = 0; e < 16; ++e) {
        bool prune;
        if (kv[e] < thr)      prune = true;
        else if (kv[e] > thr) prune = false;
        else { prune = (r < p); r += 1u; }
        if (prune) wv[e] = 0u;
    }
    *(uint4*)(wB + base)     = wraw[0];
    *(uint4*)(wB + base + 8) = wraw[1];
}

// ================= 256x256 8-phase bf16 NT GEMM (m201 template) =================
// BM=BN=256, BK=64, 8 waves (2M x 4N), LDS 128 KiB:
//   buf0 (even K-tiles): A @ 0, B @ 32768 ; buf1 (odd): A @ 65536, B @ 98304
// each tile region: [256 rows][64 cols] bf16 row-major, st_16x32 swizzled
//   (logical byte L -> physical L ^ (((L>>9)&1)<<5), i.e. col^=32 when row bit2 set)
// staging: linear global_load_lds dest + inverse-swizzled per-lane global source.
#define LA0 0
#define LB0 32768
#define LA1 65536
#define LB1 98304

__device__ __forceinline__ void gl_lds16(const char* src, char* dst) {
    __builtin_amdgcn_global_load_lds((const __attribute__((address_space(1))) void*)src,
                                     (__attribute__((address_space(3))) void*)dst, 16, 0, 0);
}

__global__ __launch_bounds__(512, 2) void gemm256_kernel(const u16* __restrict__ xB,
                                                         const u16* __restrict__ wB,
                                                         const float* __restrict__ bias,
                                                         float* __restrict__ out)
{
    __shared__ char ldsc[131072];
    const int t    = threadIdx.x;
    const int lane = t & 63;
    const int wid  = t >> 6;
    const int wm   = wid >> 2;     // 0..1
    const int wn   = wid & 3;      // 0..3
    const int bm   = blockIdx.x >> 4;    // M/256 = 32
    const int bn   = blockIdx.x & 15;    // N/256 = 16

    // ds_read fragment addressing (per-lane constant swizzle XOR: row bit2 == lane bit2)
    const int l15 = lane & 15;
    const int kb  = (lane >> 4) << 4;               // 0,16,32,48 bytes (k-group)
    const int sw  = ((lane >> 2) & 1) << 5;
    const int bA  = (((16*wm + l15) * 128 + kb) ^ sw);   // + m*4096 + kk*64
    const int bB  = (((64*wn + l15) * 128 + kb) ^ sw);   // + ni*2048 + kk*64

    // staging: thread t writes LDS linear [half*16384 + issue*8192 + t*16]
    // global source pre-swizzled: row = t>>3 (+64/issue, +128/half), colbyte = (t&7)*16 ^ (rowbit2<<5)
    const int scol = ((t & 7) * 16) ^ (((t >> 5) & 1) << 5);
    const char* pA = (const char*)xB + ((size_t)(bm*256 + (t >> 3))) * (IN_F*2) + scol;
    const char* pB = (const char*)wB + ((size_t)(bn*256 + (t >> 3))) * (IN_F*2) + scol;
    const int tb16 = t * 16;

#define STAGE(pG, reg, h, tile) do {                                          \
    const char* _s = (pG) + (size_t)(tile)*128 + (size_t)(h)*(128*IN_F*2);    \
    char* _d = ldsc + (reg) + (h)*16384 + tb16;                               \
    gl_lds16(_s, _d);                                                         \
    gl_lds16(_s + (size_t)(64*IN_F*2), _d + 8192);                            \
} while (0)

    f32x4  acc[8][4] = {};
    bf16x8 b[4][2];
    bf16x8 a[2][2];

#define LOADB(reg) do {                                                       \
    _Pragma("unroll") for (int ni = 0; ni < 4; ++ni)                          \
    _Pragma("unroll") for (int kk = 0; kk < 2; ++kk)                          \
        b[ni][kk] = *(const bf16x8*)(ldsc + (reg) + bB + ni*2048 + kk*64);    \
} while (0)

#define LOADA(reg, q) do {                                                    \
    _Pragma("unroll") for (int mm = 0; mm < 2; ++mm)                          \
    _Pragma("unroll") for (int kk = 0; kk < 2; ++kk)                          \
        a[mm][kk] = *(const bf16x8*)(ldsc + (reg) + bA + (2*(q)+mm)*4096 + kk*64); \
} while (0)

#define MFMAQ(q) do {                                                         \
    _Pragma("unroll") for (int mm = 0; mm < 2; ++mm)                          \
    _Pragma("unroll") for (int ni = 0; ni < 4; ++ni)                          \
    _Pragma("unroll") for (int kk = 0; kk < 2; ++kk)                          \
        acc[2*(q)+mm][ni] = __builtin_amdgcn_mfma_f32_16x16x32_bf16(          \
            a[mm][kk], b[ni][kk], acc[2*(q)+mm][ni], 0, 0, 0);                \
} while (0)

#define PH_TAIL(q)                                                            \
    __builtin_amdgcn_s_barrier();                                             \
    asm volatile("s_waitcnt lgkmcnt(0)" ::: "memory");                        \
    __builtin_amdgcn_s_setprio(1);                                            \
    MFMAQ(q);                                                                 \
    __builtin_amdgcn_s_setprio(0);                                            \
    __builtin_amdgcn_s_barrier();

    // ---- prologue: stage tile0 (4 half-tiles) + tile1 (B halves, A half0), in stream order
    STAGE(pB, LB0, 0, 0);
    STAGE(pB, LB0, 1, 0);
    STAGE(pA, LA0, 0, 0);
    STAGE(pA, LA0, 1, 0);
    STAGE(pB, LB1, 0, 1);
    STAGE(pB, LB1, 1, 1);
    STAGE(pA, LA1, 0, 1);
    asm volatile("s_waitcnt vmcnt(6)" ::: "memory");   // tile0's 4 half-tiles landed
    __builtin_amdgcn_s_barrier();

#pragma unroll 1
    for (int j = 0; j < IN_F/64/2; ++j) {
        const int to = 2*j + 1;
        const int se = (2*j + 2) & 63;   // wrapped: tail iterations stage garbage into free slots (safe)
        const int so = (2*j + 3) & 63;

        // ---- even tile (buf0) ----
        // ph1: quadrant 0 + B ; stage A1h1(to)  [slot free since iter j-1 ph8]
        LOADB(LB0); LOADA(LA0, 0);
        STAGE(pA, LA1, 1, to);
        asm volatile("s_waitcnt lgkmcnt(8)" ::: "memory");
        PH_TAIL(0)
        // ph2: stage B0h0(se)  [B0 free after ph1]
        LOADA(LA0, 1);
        STAGE(pB, LB0, 0, se);
        PH_TAIL(1)
        // ph3: stage B0h1(se)
        LOADA(LA0, 2);
        STAGE(pB, LB0, 1, se);
        PH_TAIL(2)
        // ph4: stage A0h0(se)  [A0h0 free after ph2]; vmcnt(6) -> odd tile fully landed
        LOADA(LA0, 3);
        STAGE(pA, LA0, 0, se);
        asm volatile("s_waitcnt vmcnt(6)" ::: "memory");
        PH_TAIL(3)

        // ---- odd tile (buf1) ----
        // ph5: quadrant 0 + B ; stage A0h1(se)  [A0h1 free after ph4]
        LOADB(LB1); LOADA(LA1, 0);
        STAGE(pA, LA0, 1, se);
        asm volatile("s_waitcnt lgkmcnt(8)" ::: "memory");
        PH_TAIL(0)
        // ph6: stage B1h0(so)  [B1 free after ph5]
        LOADA(LA1, 1);
        STAGE(pB, LB1, 0, so);
        PH_TAIL(1)
        // ph7: stage B1h1(so)
        LOADA(LA1, 2);
        STAGE(pB, LB1, 1, so);
        PH_TAIL(2)
        // ph8: stage A1h0(so)  [A1h0 free after ph6]; vmcnt(6) -> even tile fully landed
        LOADA(LA1, 3);
        STAGE(pA, LA1, 0, so);
        asm volatile("s_waitcnt vmcnt(6)" ::: "memory");
        PH_TAIL(3)
    }

    // ---- epilogue: C/D layout col=lane&15, row=(lane>>4)*4+q ; frag m at M-row 32m+16wm
    const int orow0 = bm*256 + 16*wm + ((lane >> 4) << 2);
    const int ocol0 = bn*256 + 64*wn + l15;
#pragma unroll
    for (int ni = 0; ni < 4; ++ni) {
        const int col = ocol0 + ni*16;
        const float bv = bias[col];
#pragma unroll
        for (int m = 0; m < 8; ++m) {
            const int r0 = orow0 + 32*m;
            f32x4 v = acc[m][ni];
#pragma unroll
            for (int q = 0; q < 4; ++q)
                out[(size_t)(r0 + q)*OUT_F + col] = v[q] + bv;
        }
    }
#undef STAGE
#undef LOADB
#undef LOADA
#undef MFMAQ
#undef PH_TAIL
}

extern "C" void kernel_launch(void* const* d_in, const int* in_sizes, int n_in,
                              void* d_out, int out_size, void* d_ws, size_t ws_size,
                              hipStream_t stream)
{
    const float* x    = (const float*)d_in[0];
    const float* W    = (const float*)d_in[1];
    const float* bias = (const float*)d_in[2];
    const float* U    = (const float*)d_in[3];
    const float* V    = (const float*)d_in[4];
    const float* A    = (const float*)d_in[5];
    const float* B    = (const float*)d_in[6];
    const float* R    = (const float*)d_in[7];
    const float* C    = (const float*)d_in[8];
    float* out = (float*)d_out;

    char* ws = (char*)d_ws;
    u16*      xB   = (u16*)(ws + XB_OFF);
    u16*      wB   = (u16*)(ws + WB_OFF);
    uint32_t* keys = (uint32_t*)(ws + KEYS_OFF);
    uint32_t* ctl  = (uint32_t*)(ws + CTL_OFF);
    uint32_t* h1   = (uint32_t*)((char*)ctl + H1_OFF);
    uint32_t* h2   = (uint32_t*)((char*)ctl + H2_OFF);
    uint32_t* h3   = (uint32_t*)((char*)ctl + H3_OFF);
    uint32_t* sel  = (uint32_t*)((char*)ctl + SEL_OFF);
    uint32_t* ties = (uint32_t*)((char*)ctl + TIES_OFF);

    zero_kernel<<<(CTL_ZERO_U32 + 255)/256, 256, 0, stream>>>(ctl, CTL_ZERO_U32);
    convx_kernel<<<TOKENS*IN_F/8/256, 256, 0, stream>>>(x, xB);
    prep_kernel<<<OUT_F, 256, 0, stream>>>(W, U, V, A, B, R, C, wB, keys, h1);
    select_kernel<<<1, 256, 0, stream>>>(h1, sel, 4096, 0);
    hist2_kernel<<<OUT_F, 256, 0, stream>>>(keys, sel, h2);
    select_kernel<<<1, 256, 0, stream>>>(h2, sel, 4096, 1);
    hist3_kernel<<<OUT_F, 256, 0, stream>>>(keys, sel, h3);
    select_kernel<<<1, 256, 0, stream>>>(h3, sel, 256, 2);
    tiecount_kernel<<<OUT_F, 256, 0, stream>>>(keys, sel, ties);
    scanties_kernel<<<1, 256, 0, stream>>>(ties);
    maskpack_kernel<<<OUT_F, 256, 0, stream>>>(keys, sel, ties, wB);
    gemm256_kernel<<<(TOKENS/256)*(OUT_F/256), 512, 0, stream>>>(xB, wB, bias, out);
}

// Round 3
// 434.063 us; speedup vs baseline: 1.3794x; 1.1854x over previous
//
#include <hip/hip_runtime.h>
#include <stdint.h>

#define TOKENS 8192
#define OUT_F  4096
#define IN_F   4096
#define RNK    8
#define RPB    4
#define KPRUNE 8388608u
#define TIECAP 4096u

typedef unsigned short u16;
typedef float  f32x4  __attribute__((ext_vector_type(4)));
typedef short  bf16x8 __attribute__((ext_vector_type(8)));
typedef unsigned short u16x8 __attribute__((ext_vector_type(8)));

// ---- workspace layout (bytes) ----
#define XB_OFF    0ull                 // xB  : 8192*4096 bf16 = 64 MiB
#define WB_OFF    67108864ull          // wB  : 4096*4096 bf16 = 32 MiB
#define KEYS_OFF  100663296ull         // keys: 4096*4096 u32  = 64 MiB
#define CTL_OFF   167772160ull
//   ctl: h1[4096] h2[4096] h3[256] sel[8] tiecnt[1] tieidx[TIECAP]
#define H1_OFF    0
#define H2_OFF    16384
#define H3_OFF    32768
#define SEL_OFF   33792
#define TIECNT_OFF 33824
#define TIEIDX_OFF 33828
#define CTL_ZERO_U32 8457              // through tiecnt

__device__ __forceinline__ u16 f2bf(float f) {
    uint32_t u = __float_as_uint(f);
    u += 0x7fffu + ((u >> 16) & 1u);   // RNE
    return (u16)(u >> 16);
}

__device__ __forceinline__ uint32_t fkey(float s) {
    uint32_t u = __float_as_uint(s);
    return (u & 0x80000000u) ? ~u : (u | 0x80000000u);
}

// ---------------- x -> bf16 (+ ctl zeroing folded in) ----------------
__global__ void convx_kernel(const float* __restrict__ x, u16* __restrict__ xB,
                             uint32_t* __restrict__ ctl)
{
    const int t = threadIdx.x;
    if (blockIdx.x < 34) {
        const int i = blockIdx.x * 256 + t;
        if (i < CTL_ZERO_U32) ctl[i] = 0u;
    }
    const size_t idx = (size_t)blockIdx.x * 256 + t;
    const float4* xv = (const float4*)x;
    float4 a = xv[idx*2];
    float4 b = xv[idx*2 + 1];
    u16x8 o;
    o[0]=f2bf(a.x); o[1]=f2bf(a.y); o[2]=f2bf(a.z); o[3]=f2bf(a.w);
    o[4]=f2bf(b.x); o[5]=f2bf(b.y); o[6]=f2bf(b.z); o[7]=f2bf(b.w);
    *((u16x8*)xB + idx) = o;
}

// ---------------- prep: w, keys, bf16 w, 12-bit histogram (4 rows/block) ----------------
__global__ void prep_kernel(const float* __restrict__ W, const float* __restrict__ U,
                            const float* __restrict__ V, const float* __restrict__ A,
                            const float* __restrict__ B, const float* __restrict__ R,
                            const float* __restrict__ C, u16* __restrict__ wB,
                            uint32_t* __restrict__ keys, uint32_t* __restrict__ hist1)
{
    __shared__ uint32_t lh[4096];
    const int o0 = blockIdx.x * RPB, t = threadIdx.x;
    for (int b = t; b < 4096; b += 256) lh[b] = 0u;
    float uu[RPB][RNK], aa[RPB][RNK], ro[RPB];
#pragma unroll
    for (int r0 = 0; r0 < RPB; ++r0) {
#pragma unroll
        for (int r = 0; r < RNK; ++r) {
            uu[r0][r] = U[(o0+r0)*RNK + r];
            aa[r0][r] = A[(o0+r0)*RNK + r];
        }
        ro[r0] = R[o0 + r0];
    }
    __syncthreads();
    for (int j = 0; j < IN_F/256; ++j) {
        const int i = j*256 + t;
        float vv[RNK], bb[RNK];
#pragma unroll
        for (int r = 0; r < RNK; ++r) { vv[r] = V[r*IN_F + i]; bb[r] = B[r*IN_F + i]; }
        const float ci = C[i];
#pragma unroll
        for (int r0 = 0; r0 < RPB; ++r0) {
            float wv = W[(size_t)(o0+r0)*IN_F + i];
#pragma unroll
            for (int r = 0; r < RNK; ++r) wv = fmaf(uu[r0][r], vv[r], wv);
            float s = fabsf(wv);
#pragma unroll
            for (int r = 0; r < RNK; ++r) s = fmaf(aa[r0][r], bb[r], s);
            s += ro[r0] + ci;
            const uint32_t key = fkey(s);
            keys[(size_t)(o0+r0)*IN_F + i] = key;
            wB[(size_t)(o0+r0)*IN_F + i]   = f2bf(wv);
            atomicAdd(&lh[key >> 20], 1u);
        }
    }
    __syncthreads();
    for (int b = t; b < 4096; b += 256) { uint32_t c = lh[b]; if (c) atomicAdd(&hist1[b], c); }
}

// ---------------- k-th select over a histogram ----------------
__global__ void select_kernel(const uint32_t* __restrict__ hist, uint32_t* sel, int nbins, int mode)
{
    __shared__ uint32_t lh[4096];
    __shared__ uint32_t part[256];
    __shared__ uint32_t sseg[2];
    const int t = threadIdx.x;
    const uint32_t b1v = sel[0], c1v = sel[1], b2v = sel[2], c3v = sel[3];
    uint32_t k;
    if (mode == 0)      k = KPRUNE;
    else if (mode == 1) k = KPRUNE - c1v;
    else                k = KPRUNE - c3v;
    for (int b = t; b < nbins; b += 256) lh[b] = hist[b];
    __syncthreads();
    const int per = nbins >> 8;
    uint32_t s = 0;
    for (int j = 0; j < per; ++j) s += lh[t*per + j];
    part[t] = s;
    __syncthreads();
    uint32_t pre = 0;
    for (int tt = 0; tt < t; ++tt) pre += part[tt];
    if (pre < k && pre + part[t] >= k) { sseg[0] = (uint32_t)t; sseg[1] = pre; }
    __syncthreads();
    const int seg = (int)sseg[0];
    const uint32_t accb = sseg[1];
    if (t < per) {
        uint32_t pre2 = 0;
        for (int j = 0; j < t; ++j) pre2 += lh[seg*per + j];
        const uint32_t c = lh[seg*per + t];
        const uint32_t below = accb + pre2;
        if (below < k && below + c >= k) {
            const uint32_t bin = (uint32_t)(seg*per + t);
            if (mode == 0)      { sel[0] = bin; sel[1] = below; }
            else if (mode == 1) { sel[2] = bin; sel[3] = c1v + below; }
            else {
                sel[4] = (b1v << 20) | (b2v << 8) | bin;
                sel[5] = k - below;   // ties to prune (>=1)
            }
        }
    }
}

// ---------------- hist level 2 ----------------
__global__ void hist2_kernel(const uint32_t* __restrict__ keys, const uint32_t* __restrict__ sel,
                             uint32_t* __restrict__ hist2)
{
    __shared__ uint32_t lh[4096];
    const int o = blockIdx.x, t = threadIdx.x;
    const uint32_t b1 = sel[0];
    for (int b = t; b < 4096; b += 256) lh[b] = 0u;
    __syncthreads();
    const uint32_t* kp = keys + (size_t)o*IN_F + t*16;
#pragma unroll
    for (int q = 0; q < 4; ++q) {
        uint4 kv = *(const uint4*)(kp + q*4);
        if ((kv.x >> 20) == b1) atomicAdd(&lh[(kv.x >> 8) & 0xFFFu], 1u);
        if ((kv.y >> 20) == b1) atomicAdd(&lh[(kv.y >> 8) & 0xFFFu], 1u);
        if ((kv.z >> 20) == b1) atomicAdd(&lh[(kv.z >> 8) & 0xFFFu], 1u);
        if ((kv.w >> 20) == b1) atomicAdd(&lh[(kv.w >> 8) & 0xFFFu], 1u);
    }
    __syncthreads();
    for (int b = t; b < 4096; b += 256) { uint32_t c = lh[b]; if (c) atomicAdd(&hist2[b], c); }
}

// ---------------- hist level 3 ----------------
__global__ void hist3_kernel(const uint32_t* __restrict__ keys, const uint32_t* __restrict__ sel,
                             uint32_t* __restrict__ hist3)
{
    __shared__ uint32_t lh[256];
    const int o = blockIdx.x, t = threadIdx.x;
    const uint32_t pfx = (sel[0] << 12) | sel[2];
    lh[t] = 0u;
    __syncthreads();
    const uint32_t* kp = keys + (size_t)o*IN_F + t*16;
#pragma unroll
    for (int q = 0; q < 4; ++q) {
        uint4 kv = *(const uint4*)(kp + q*4);
        if ((kv.x >> 8) == pfx) atomicAdd(&lh[kv.x & 0xFFu], 1u);
        if ((kv.y >> 8) == pfx) atomicAdd(&lh[kv.y & 0xFFu], 1u);
        if ((kv.z >> 8) == pfx) atomicAdd(&lh[kv.z & 0xFFu], 1u);
        if ((kv.w >> 8) == pfx) atomicAdd(&lh[kv.w & 0xFFu], 1u);
    }
    __syncthreads();
    uint32_t c = lh[t];
    if (c) atomicAdd(&hist3[t], c);
}

// ---------------- apply: prune key<thr, append tie indices ----------------
__global__ void apply_kernel(const uint32_t* __restrict__ keys, const uint32_t* __restrict__ sel,
                             u16* __restrict__ wB, uint32_t* __restrict__ tiecnt,
                             uint32_t* __restrict__ tieidx)
{
    const uint32_t thr = sel[4];
    const size_t base = ((size_t)blockIdx.x * 256 + threadIdx.x) * 16;
    uint32_t kv[16];
#pragma unroll
    for (int q = 0; q < 4; ++q) *(uint4*)(kv + q*4) = *(const uint4*)(keys + base + q*4);
    uint4 wraw[2];
    wraw[0] = *(const uint4*)(wB + base);
    wraw[1] = *(const uint4*)(wB + base + 8);
    u16* wv = (u16*)wraw;
#pragma unroll
    for (int e = 0; e < 16; ++e) {
        if (kv[e] < thr) wv[e] = 0u;
        else if (kv[e] == thr) {
            uint32_t slot = atomicAdd(tiecnt, 1u);
            if (slot < TIECAP) tieidx[slot] = (uint32_t)(base + e);
        }
    }
    *(uint4*)(wB + base)     = wraw[0];
    *(uint4*)(wB + base + 8) = wraw[1];
}

// ---------------- fixties: zero the p earliest-flat-index ties ----------------
__global__ void fixties_kernel(const uint32_t* __restrict__ sel, const uint32_t* __restrict__ tiecnt,
                               const uint32_t* __restrict__ tieidx, u16* __restrict__ wB)
{
    const uint32_t p = sel[5];
    uint32_t n = *tiecnt; if (n > TIECAP) n = TIECAP;
    for (uint32_t i = threadIdx.x; i < n; i += 256) {
        const uint32_t my = tieidx[i];
        uint32_t rank = 0;
        for (uint32_t j = 0; j < n; ++j) rank += (tieidx[j] < my) ? 1u : 0u;
        if (rank < p) wB[my] = 0u;
    }
}

// ================= 256x256 8-phase bf16 NT GEMM =================
// BM=BN=256, BK=64, 8 waves (2M x 4N), LDS 128 KiB:
//   buf0 (even K-tiles): A @ 0, B @ 32768 ; buf1 (odd): A @ 65536, B @ 98304
// each tile region: [256 rows][64 cols] bf16 row-major.
// T2 swizzle (3-bit, bank-period-aware): physical byte = logical ^ ((row&7)<<4),
// applied AFTER the full logical offset (kk*64 carries into swizzled bits otherwise).
// Staging: linear global_load_lds dest + inverse-swizzled per-lane global source.
#define LA0 0
#define LB0 32768
#define LA1 65536
#define LB1 98304

__device__ __forceinline__ void gl_lds16(const char* src, char* dst) {
    __builtin_amdgcn_global_load_lds((const __attribute__((address_space(1))) void*)src,
                                     (__attribute__((address_space(3))) void*)dst, 16, 0, 0);
}

__global__ __launch_bounds__(512, 2) void gemm256_kernel(const u16* __restrict__ xB,
                                                         const u16* __restrict__ wB,
                                                         const float* __restrict__ bias,
                                                         float* __restrict__ out)
{
    __shared__ char ldsc[131072];
    const int t    = threadIdx.x;
    const int lane = t & 63;
    const int wid  = t >> 6;
    const int wm   = wid >> 2;     // 0..1
    const int wn   = wid & 3;      // 0..3
    const int bm   = blockIdx.x >> 4;    // M/256 = 32
    const int bn   = blockIdx.x & 15;    // N/256 = 16

    // ds_read fragment addressing; row&7 == lane&7 for both A and B fragments
    const int l15 = lane & 15;
    const int kb  = (lane >> 4) << 4;               // 0,16,32,48 bytes (k-group)
    const int sw  = (lane & 7) << 4;                // 3-bit XOR swizzle
    const int bA  = (16*wm + l15) * 128 + kb;       // + m*4096 + kk*64, then ^ sw
    const int bB  = (64*wn + l15) * 128 + kb;       // + ni*2048 + kk*64, then ^ sw

    // staging: thread t writes LDS linear [half*16384 + issue*8192 + t*16]
    // global source pre-swizzled: row = t>>3 (+64/issue, +128/half); (row&7) = (t>>3)&7
    const int scol = ((t & 7) * 16) ^ (((t >> 3) & 7) << 4);
    const char* pA = (const char*)xB + ((size_t)(bm*256 + (t >> 3))) * (IN_F*2) + scol;
    const char* pB = (const char*)wB + ((size_t)(bn*256 + (t >> 3))) * (IN_F*2) + scol;
    const int tb16 = t * 16;

#define STAGE(pG, reg, h, tile) do {                                          \
    const char* _s = (pG) + (size_t)(tile)*128 + (size_t)(h)*(128*IN_F*2);    \
    char* _d = ldsc + (reg) + (h)*16384 + tb16;                               \
    gl_lds16(_s, _d);                                                         \
    gl_lds16(_s + (size_t)(64*IN_F*2), _d + 8192);                            \
} while (0)

    f32x4  acc[8][4] = {};
    bf16x8 b[4][2];
    bf16x8 a[2][2];

#define LOADB(reg) do {                                                       \
    _Pragma("unroll") for (int ni = 0; ni < 4; ++ni)                          \
    _Pragma("unroll") for (int kk = 0; kk < 2; ++kk)                          \
        b[ni][kk] = *(const bf16x8*)(ldsc + (reg) +                           \
                      ((bB + ni*2048 + kk*64) ^ sw));                         \
} while (0)

#define LOADA(reg, q) do {                                                    \
    _Pragma("unroll") for (int mm = 0; mm < 2; ++mm)                          \
    _Pragma("unroll") for (int kk = 0; kk < 2; ++kk)                          \
        a[mm][kk] = *(const bf16x8*)(ldsc + (reg) +                           \
                      ((bA + (2*(q)+mm)*4096 + kk*64) ^ sw));                 \
} while (0)

#define MFMAQ(q) do {                                                         \
    _Pragma("unroll") for (int mm = 0; mm < 2; ++mm)                          \
    _Pragma("unroll") for (int ni = 0; ni < 4; ++ni)                          \
    _Pragma("unroll") for (int kk = 0; kk < 2; ++kk)                          \
        acc[2*(q)+mm][ni] = __builtin_amdgcn_mfma_f32_16x16x32_bf16(          \
            a[mm][kk], b[ni][kk], acc[2*(q)+mm][ni], 0, 0, 0);                \
} while (0)

#define PH_TAIL(q)                                                            \
    __builtin_amdgcn_s_barrier();                                             \
    asm volatile("s_waitcnt lgkmcnt(0)" ::: "memory");                        \
    __builtin_amdgcn_s_setprio(1);                                            \
    MFMAQ(q);                                                                 \
    __builtin_amdgcn_s_setprio(0);                                            \
    __builtin_amdgcn_s_barrier();

    // ---- prologue: stage tile0 (4 half-tiles) + tile1 (B halves, A half0)
    STAGE(pB, LB0, 0, 0);
    STAGE(pB, LB0, 1, 0);
    STAGE(pA, LA0, 0, 0);
    STAGE(pA, LA0, 1, 0);
    STAGE(pB, LB1, 0, 1);
    STAGE(pB, LB1, 1, 1);
    STAGE(pA, LA1, 0, 1);
    asm volatile("s_waitcnt vmcnt(6)" ::: "memory");   // tile0's 4 half-tiles landed
    __builtin_amdgcn_s_barrier();

#pragma unroll 1
    for (int j = 0; j < IN_F/64/2; ++j) {
        const int to = 2*j + 1;
        const int se = (2*j + 2) & 63;   // wrapped tail staging targets free slots (safe)
        const int so = (2*j + 3) & 63;

        // ---- even tile (buf0) ----
        LOADB(LB0); LOADA(LA0, 0);
        STAGE(pA, LA1, 1, to);
        asm volatile("s_waitcnt lgkmcnt(8)" ::: "memory");
        PH_TAIL(0)
        LOADA(LA0, 1);
        STAGE(pB, LB0, 0, se);
        PH_TAIL(1)
        LOADA(LA0, 2);
        STAGE(pB, LB0, 1, se);
        PH_TAIL(2)
        LOADA(LA0, 3);
        STAGE(pA, LA0, 0, se);
        asm volatile("s_waitcnt vmcnt(6)" ::: "memory");
        PH_TAIL(3)

        // ---- odd tile (buf1) ----
        LOADB(LB1); LOADA(LA1, 0);
        STAGE(pA, LA0, 1, se);
        asm volatile("s_waitcnt lgkmcnt(8)" ::: "memory");
        PH_TAIL(0)
        LOADA(LA1, 1);
        STAGE(pB, LB1, 0, so);
        PH_TAIL(1)
        LOADA(LA1, 2);
        STAGE(pB, LB1, 1, so);
        PH_TAIL(2)
        LOADA(LA1, 3);
        STAGE(pA, LA1, 0, so);
        asm volatile("s_waitcnt vmcnt(6)" ::: "memory");
        PH_TAIL(3)
    }

    // ---- epilogue: C/D layout col=lane&15, row=(lane>>4)*4+q ; frag m at M-row 32m+16wm
    const int orow0 = bm*256 + 16*wm + ((lane >> 4) << 2);
    const int ocol0 = bn*256 + 64*wn + l15;
#pragma unroll
    for (int ni = 0; ni < 4; ++ni) {
        const int col = ocol0 + ni*16;
        const float bv = bias[col];
#pragma unroll
        for (int m = 0; m < 8; ++m) {
            const int r0 = orow0 + 32*m;
            f32x4 v = acc[m][ni];
#pragma unroll
            for (int q = 0; q < 4; ++q)
                out[(size_t)(r0 + q)*OUT_F + col] = v[q] + bv;
        }
    }
#undef STAGE
#undef LOADB
#undef LOADA
#undef MFMAQ
#undef PH_TAIL
}

extern "C" void kernel_launch(void* const* d_in, const int* in_sizes, int n_in,
                              void* d_out, int out_size, void* d_ws, size_t ws_size,
                              hipStream_t stream)
{
    const float* x    = (const float*)d_in[0];
    const float* W    = (const float*)d_in[1];
    const float* bias = (const float*)d_in[2];
    const float* U    = (const float*)d_in[3];
    const float* V    = (const float*)d_in[4];
    const float* A    = (const float*)d_in[5];
    const float* B    = (const float*)d_in[6];
    const float* R    = (const float*)d_in[7];
    const float* C    = (const float*)d_in[8];
    float* out = (float*)d_out;

    char* ws = (char*)d_ws;
    u16*      xB   = (u16*)(ws + XB_OFF);
    u16*      wB   = (u16*)(ws + WB_OFF);
    uint32_t* keys = (uint32_t*)(ws + KEYS_OFF);
    uint32_t* ctl  = (uint32_t*)(ws + CTL_OFF);
    uint32_t* h1   = (uint32_t*)((char*)ctl + H1_OFF);
    uint32_t* h2   = (uint32_t*)((char*)ctl + H2_OFF);
    uint32_t* h3   = (uint32_t*)((char*)ctl + H3_OFF);
    uint32_t* sel  = (uint32_t*)((char*)ctl + SEL_OFF);
    uint32_t* tiecnt = (uint32_t*)((char*)ctl + TIECNT_OFF);
    uint32_t* tieidx = (uint32_t*)((char*)ctl + TIEIDX_OFF);

    convx_kernel<<<TOKENS*IN_F/8/256, 256, 0, stream>>>(x, xB, ctl);
    prep_kernel<<<OUT_F/RPB, 256, 0, stream>>>(W, U, V, A, B, R, C, wB, keys, h1);
    select_kernel<<<1, 256, 0, stream>>>(h1, sel, 4096, 0);
    hist2_kernel<<<OUT_F, 256, 0, stream>>>(keys, sel, h2);
    select_kernel<<<1, 256, 0, stream>>>(h2, sel, 4096, 1);
    hist3_kernel<<<OUT_F, 256, 0, stream>>>(keys, sel, h3);
    select_kernel<<<1, 256, 0, stream>>>(h3, sel, 256, 2);
    apply_kernel<<<OUT_F, 256, 0, stream>>>(keys, sel, wB, tiecnt, tieidx);
    fixties_kernel<<<1, 256, 0, stream>>>(sel, tiecnt, tieidx, wB);
    gemm256_kernel<<<(TOKENS/256)*(OUT_F/256), 512, 0, stream>>>(xB, wB, bias, out);
}